// Round 10
// baseline (1963.172 us; speedup 1.0000x reference)
//
#include <hip/hip_runtime.h>
#include <hip/hip_bf16.h>
#include <stdint.h>

typedef __attribute__((ext_vector_type(8))) short short8;
typedef __attribute__((ext_vector_type(4))) float f32x4;
typedef unsigned short bfu;

#define T_TILE  128
#define RING    384            // ring rows; invariant: (max staged row - t0) < 384 per tile
#define NLAYERS 16
#define T0LEN   131072
#define BATCH   8
#define RFIELD  510            // sum of dilations
#define FINLEN  130560         // 510 pool windows * 256
#define CHCAP   65280          // chunk cap: 2x bf16 buffers (~135MB) stay L3-resident

// lgkm-only barrier (LDS visibility); global loads/stores stay in flight.
#define BARRIER() asm volatile("s_waitcnt lgkmcnt(0)\n\ts_barrier" ::: "memory")
// end-of-tile publish: drain ALL vmem (stage gload_lds complete -> ring valid for
// all waves after barrier).
#define PUBLISH() asm volatile("s_waitcnt vmcnt(0) lgkmcnt(0)\n\ts_barrier" ::: "memory")

__device__ __forceinline__ bfu f2bf(float f) {
    unsigned u = __float_as_uint(f);
    u += 0x7FFFu + ((u >> 16) & 1u);      // RNE
    return (bfu)(u >> 16);
}
__device__ __forceinline__ float bf2f(bfu h) { return __uint_as_float(((unsigned)h) << 16); }
__device__ __forceinline__ unsigned relu2(unsigned w) {
    return w & ~(((w >> 15) & 0x00010001u) * 0xFFFFu);
}
__device__ __forceinline__ short8 relu8(short8 v) {
    uint4 u = *(uint4*)&v;
    u.x = relu2(u.x); u.y = relu2(u.y); u.z = relu2(u.z); u.w = relu2(u.w);
    return *(short8*)&u;
}

// async-stage one 8-row group (1KB) into the ring via global_load_lds width=16.
// LDS dest is linear (base + lane*16); the XOR swizzle is realized by pre-swizzling
// the per-lane GLOBAL source column group (involution), so the swizzled READ matches.
__device__ __forceinline__ void stage_group(const bfu* __restrict__ xb, bfu* ldsb,
                                            int r0, int rs0, int Lin, int lane)
{
    int  sub = lane >> 3;                      // row within group 0..7
    long t   = r0 + sub; if (t > Lin - 1) t = Lin - 1;
    int  srcoc = (lane & 7) ^ ((rs0 + sub) & 7);
    const bfu* g = xb + t * 64 + srcoc * 8;
    __builtin_amdgcn_global_load_lds((const void*)g, (void*)ldsb, 16, 0, 0);
}

// ---- weights: Wd[l][o][c][tap] -> wcat[l][o][k] bf16 (k=tap*64+c); Wr -> wrb bf16
__global__ void prep_weights(const float* __restrict__ Wd, const float* __restrict__ Wr,
                             bfu* __restrict__ wcat, bfu* __restrict__ wrb)
{
    int idx = blockIdx.x * 256 + threadIdx.x;
    const int total1 = NLAYERS * 128 * 128;
    if (idx < total1) {
        int k = idx & 127, o = (idx >> 7) & 127, l = idx >> 14;
        int tap = k >> 6, c = k & 63;
        wcat[idx] = f2bf(Wd[(((l * 128 + o) * 64) + c) * 2 + tap]);
    } else {
        int j = idx - total1;
        if (j < NLAYERS * 64 * 128) wrb[j] = f2bf(Wr[j]);
    }
}

// MODE: 0 = middle, 1 = first (input conv fused; d==1), 2 = last (final conv+pool fused)
template <int MODE>
__global__ __launch_bounds__(256, 2)
void layer_kernel(const bfu* __restrict__ xin, bfu* __restrict__ xout,
                  const bfu* __restrict__ wcat, const bfu* __restrict__ wrb,
                  const float* __restrict__ bd, const float* __restrict__ br,
                  const float* __restrict__ sig, const float* __restrict__ W0,
                  const float* __restrict__ b0, const float* __restrict__ Wf,
                  float* __restrict__ partial,
                  int s, int d, int Lin, int Lout, int Rrows, int NT, int tiles)
{
    __shared__ bfu rx[RING * 64];      // 48 KB ring: RAW x bf16 (relu on read), swizzled slots
    __shared__ bfu hb[128 * 128];      // 32 KB: relu(h+bd) bf16, swizzled

    const int tid  = threadIdx.x;
    const int lane = tid & 63;
    const int wv   = tid >> 6;
    const int l15  = lane & 15;
    const int lg   = lane >> 4;
    const int b    = blockIdx.y;

    const bfu* xb = xin  + (long)b * Rrows * 64;
    bfu*       xo = xout + (long)b * Rrows * 64;
    const float* sgb = sig + (long)b * T0LEN + s;

    // ---- loop-invariant: weight A-fragments, biases ----
    short8 a1[2][4];
    #pragma unroll
    for (int m = 0; m < 2; ++m)
        #pragma unroll
        for (int k = 0; k < 4; ++k)
            a1[m][k] = *(const short8*)(wcat + ((wv * 32 + m * 16 + l15) << 7) + (k << 5) + (lg << 3));
    short8 a2[4];
    #pragma unroll
    for (int k = 0; k < 4; ++k)
        a2[k] = *(const short8*)(wrb + ((wv * 16 + l15) << 7) + (k << 5) + (lg << 3));

    const int c0 = wv * 16 + lg * 4;
    const f32x4 brv = *(const f32x4*)(br + c0);
    f32x4 bd4[2];
    #pragma unroll
    for (int m = 0; m < 2; ++m)
        bd4[m] = *(const f32x4*)(bd + wv * 32 + m * 16 + lg * 4);
    f32x4 wfv;
    if constexpr (MODE == 2) wfv = *(const f32x4*)(Wf + c0);

    const int tile0 = blockIdx.x * NT;
    const int jmax  = (tiles - tile0 < NT) ? (tiles - tile0) : NT;
    const int t00   = tile0 * T_TILE;

    // ---- prologue: stage rows [t00, t00+T_TILE+d) into ring ----
    if constexpr (MODE == 1) {
        // compute relu(W0*sig+b0) rows (d==1): 129 rows; ring holds RELU'd values here
        const int nsl = (T_TILE + 1) * 8;
        #pragma unroll
        for (int it = 0; it < 5; ++it) {
            int i = tid + it * 256;
            if (i < nsl) {
                int r = i >> 3, oc = i & 7;
                int t = t00 + r; if (t > Lin - 1) t = Lin - 1;
                float sv = sgb[t];
                unsigned pk[4];
                #pragma unroll
                for (int kk = 0; kk < 4; ++kk) {
                    int c = oc * 8 + kk * 2;
                    pk[kk] = (unsigned)f2bf(fmaxf(W0[c] * sv + b0[c], 0.f))
                           | ((unsigned)f2bf(fmaxf(W0[c + 1] * sv + b0[c + 1], 0.f)) << 16);
                }
                int rs = (t00 + r) % RING;
                uint4 u; u.x = pk[0]; u.y = pk[1]; u.z = pk[2]; u.w = pk[3];
                *(uint4*)&rx[(rs << 6) + ((oc ^ (rs & 7)) << 3)] = u;
            }
        }
        BARRIER();
    } else {
        const int sc = (T_TILE + d + 7) >> 3;         // 8-row groups, <= 32
        for (int i = wv; i < sc; i += 4) {
            int r0  = t00 + i * 8;
            int rs0 = r0 % RING;
            stage_group(xb, &rx[rs0 << 6], r0, rs0, Lin, lane);
        }
        PUBLISH();
    }

    for (int j = 0; j < jmax; ++j) {
        const int t0    = t00 + j * T_TILE;
        const int base0 = t0 % RING;
        const bool havePF = (j + 1 < jmax);

        // ---- async-stage tile j+1's rows (in flight through both GEMMs) ----
        float pfs[4];
        if constexpr (MODE == 1) {
            if (havePF) {
                #pragma unroll
                for (int it = 0; it < 4; ++it) {
                    int i = tid + it * 256;
                    int t = (t0 + T_TILE + 1) + (i >> 3); if (t > Lin - 1) t = Lin - 1;
                    pfs[it] = sgb[t];
                }
            }
        } else {
            if (havePF) {
                const int rb    = t0 + T_TILE + d;
                const int start = rb & ~7;
                // RING-WRAP FIX (round 8 bug): stage exactly 16 groups when rb is
                // 8-aligned (all d>=8). 17 groups at d=128 wrapped rows t0+384..391
                // onto slots t0..t0+7 which GEMM1 was still reading. Span check:
                // aligned: max row = rb+127 = t0+255+d <= t0+383 (d<=128) < RING.
                // unaligned (d in {1,2,4}): max row = start+135 <= t0+266 < RING.
                const int ng = (rb & 7) ? 17 : 16;
                const int sb = start % RING;
                for (int i = wv; i < ng; i += 4) {
                    int rs0 = sb + i * 8; if (rs0 >= RING) rs0 -= RING;
                    stage_group(xb, &rx[rs0 << 6], start + i * 8, rs0, Lin, lane);
                }
            }
        }

        // ---- GEMM1: H[o][t] = sum_k Wcat[o][k] * relu(X)[k][t], B from ring ----
        f32x4 acc[2][8] = {};
        #pragma unroll
        for (int k = 0; k < 4; ++k) {
            const int roff = (k >> 1) ? d : 0;
            const int g    = ((k & 1) << 2) + lg;
            #pragma unroll
            for (int n = 0; n < 8; ++n) {
                int rr = base0 + n * 16 + l15 + roff;
                if (rr >= RING) rr -= RING;
                short8 bv = *(const short8*)&rx[(rr << 6) + ((g ^ (rr & 7)) << 3)];
                if constexpr (MODE != 1) bv = relu8(bv);   // ring holds raw x
                acc[0][n] = __builtin_amdgcn_mfma_f32_16x16x32_bf16(a1[0][k], bv, acc[0][n], 0, 0, 0);
                acc[1][n] = __builtin_amdgcn_mfma_f32_16x16x32_bf16(a1[1][k], bv, acc[1][n], 0, 0, 0);
            }
        }

        // ---- epilogue 1: +bd, relu, bf16 -> hb swizzled ----
        #pragma unroll
        for (int m = 0; m < 2; ++m) {
            const int o0 = wv * 32 + m * 16 + lg * 4;
            const int gg = o0 >> 3;
            #pragma unroll
            for (int n = 0; n < 8; ++n) {
                int t = n * 16 + l15;
                f32x4 h = acc[m][n];
                unsigned q01 = (unsigned)f2bf(fmaxf(h.x + bd4[m].x, 0.f)) | ((unsigned)f2bf(fmaxf(h.y + bd4[m].y, 0.f)) << 16);
                unsigned q23 = (unsigned)f2bf(fmaxf(h.z + bd4[m].z, 0.f)) | ((unsigned)f2bf(fmaxf(h.w + bd4[m].w, 0.f)) << 16);
                int idx = (t << 7) + (((gg ^ (t & 15)) << 3) | (o0 & 7));
                uint2 pk; pk.x = q01; pk.y = q23;
                *(uint2*)&hb[idx] = pk;
            }
        }

        // ---- MODE1: compute+write tile j+1's ring rows (relu'd) ----
        if constexpr (MODE == 1) {
            if (havePF) {
                const int rbase = t0 + T_TILE + 1;
                #pragma unroll
                for (int it = 0; it < 4; ++it) {
                    int i = tid + it * 256;
                    int r = i >> 3, oc = i & 7;
                    float sv = pfs[it];
                    unsigned pk[4];
                    #pragma unroll
                    for (int kk = 0; kk < 4; ++kk) {
                        int c = oc * 8 + kk * 2;
                        pk[kk] = (unsigned)f2bf(fmaxf(W0[c] * sv + b0[c], 0.f))
                               | ((unsigned)f2bf(fmaxf(W0[c + 1] * sv + b0[c + 1], 0.f)) << 16);
                    }
                    int rs = (rbase + r) % RING;
                    uint4 u; u.x = pk[0]; u.y = pk[1]; u.z = pk[2]; u.w = pk[3];
                    *(uint4*)&rx[(rs << 6) + ((oc ^ (rs & 7)) << 3)] = u;
                }
            }
        }

        BARRIER();   // hb visible (and MODE1 ring writes)

        // ---- GEMM2: Y[r][t] = sum_o Wr[r][o] * Hb[o][t] ----
        f32x4 acc2[8] = {};
        #pragma unroll
        for (int k = 0; k < 4; ++k) {
            const int g = (k << 2) + lg;
            #pragma unroll
            for (int n = 0; n < 8; ++n) {
                int t = n * 16 + l15;
                short8 bfm = *(const short8*)&hb[(t << 7) + ((g ^ (t & 15)) << 3)];
                acc2[n] = __builtin_amdgcn_mfma_f32_16x16x32_bf16(a2[k], bfm, acc2[n], 0, 0, 0);
            }
        }

        // ---- epilogue 2: +br +skip (skip from ring LDS); store bf16 or fused Wf-dot ----
        const int ocs = c0 >> 3;
        const int wo  = c0 & 7;
        float psum = 0.f;
        #pragma unroll
        for (int n = 0; n < 8; ++n) {
            int t = t0 + n * 16 + l15;
            if (t < Lout) {
                float s0, s1, s2, s3;
                if constexpr (MODE == 1) {
                    float sv = sgb[t + 1];
                    s0 = W0[c0] * sv + b0[c0];         s1 = W0[c0 + 1] * sv + b0[c0 + 1];
                    s2 = W0[c0 + 2] * sv + b0[c0 + 2]; s3 = W0[c0 + 3] * sv + b0[c0 + 3];
                } else {
                    int rr2 = base0 + n * 16 + l15 + d;
                    if (rr2 >= RING) rr2 -= RING;
                    uint2 sv = *(const uint2*)&rx[(rr2 << 6) + ((ocs ^ (rr2 & 7)) << 3) + wo];
                    s0 = bf2f((bfu)(sv.x & 0xFFFF)); s1 = bf2f((bfu)(sv.x >> 16));
                    s2 = bf2f((bfu)(sv.y & 0xFFFF)); s3 = bf2f((bfu)(sv.y >> 16));
                }
                float y0 = acc2[n].x + brv.x + s0;
                float y1 = acc2[n].y + brv.y + s1;
                float y2 = acc2[n].z + brv.z + s2;
                float y3 = acc2[n].w + brv.w + s3;
                if constexpr (MODE == 2) {
                    psum += wfv.x * y0 + wfv.y * y1 + wfv.z * y2 + wfv.w * y3;
                } else {
                    uint2 pk;
                    pk.x = (unsigned)f2bf(y0) | ((unsigned)f2bf(y1) << 16);
                    pk.y = (unsigned)f2bf(y2) | ((unsigned)f2bf(y3) << 16);
                    *(uint2*)(xo + (long)t * 64 + c0) = pk;
                }
            }
        }
        if constexpr (MODE == 2) {
            #pragma unroll
            for (int off = 32; off > 0; off >>= 1) psum += __shfl_down(psum, off, 64);
            if (lane == 0)
                partial[((long)b * 1024 + ((s + t0) >> 7)) * 4 + wv] = psum;   // per-wave
        }

        PUBLISH();   // ring rows for tile j+1 valid for ALL waves; hb free
    }
}

// ---- final: out[b][w] = (sum of 8 wave-partials over 2 tiles)/256 + bf ----
__global__ void pool_reduce(const float* __restrict__ part, const float* __restrict__ bfp,
                            float* __restrict__ out)
{
    int i = blockIdx.x * 256 + threadIdx.x;
    if (i >= BATCH * 510) return;
    int b = i / 510, w = i % 510;
    const float* p = part + ((long)b * 1024 + 2 * w) * 4;
    float sum = p[0] + p[1] + p[2] + p[3] + p[4] + p[5] + p[6] + p[7];
    out[i] = sum * (1.0f / 256.0f) + bfp[0];
}

extern "C" void kernel_launch(void* const* d_in, const int* in_sizes, int n_in,
                              void* d_out, int out_size, void* d_ws, size_t ws_size,
                              hipStream_t stream) {
    const float* sig = (const float*)d_in[0];
    const float* W0  = (const float*)d_in[1];
    const float* b0  = (const float*)d_in[2];
    const float* Wd  = (const float*)d_in[3];
    const float* bd  = (const float*)d_in[4];
    const float* Wr  = (const float*)d_in[5];
    const float* br  = (const float*)d_in[6];
    const float* Wf  = (const float*)d_in[7];
    const float* bf  = (const float*)d_in[8];
    float* out = (float*)d_out;

    // ---- workspace: [wcat | wrb | partial | xA | xB] ----
    char* ws = (char*)d_ws;
    const size_t WCAT_E = (size_t)NLAYERS * 128 * 128;
    const size_t WRB_E  = (size_t)NLAYERS * 64 * 128;
    const size_t WBYTES = (WCAT_E + WRB_E) * 2;          // 786432
    const size_t PARTB  = (size_t)BATCH * 1024 * 4 * 4;  // 131072
    bfu*   wcat    = (bfu*)ws;
    bfu*   wrb     = (bfu*)(ws + WCAT_E * 2);
    float* partial = (float*)(ws + WBYTES);

    if (ws_size < WBYTES + PARTB + (size_t)2 * BATCH * 766 * 64 * 2) return;

    size_t avail   = ws_size - WBYTES - PARTB;
    long   rowsMax = (long)(avail / ((size_t)2 * BATCH * 64 * 2));
    long   CH      = ((rowsMax - RFIELD) / 256) * 256;
    if (CH > CHCAP) CH = CHCAP;        // L3 blocking
    if (CH < 256)   CH = 256;
    const long Rrows = CH + RFIELD;

    bfu* xA = (bfu*)(ws + WBYTES + PARTB);
    bfu* xB = xA + (size_t)BATCH * Rrows * 64;

    const int totw = (int)(WCAT_E + WRB_E);
    prep_weights<<<(totw + 255) / 256, 256, 0, stream>>>(Wd, Wr, wcat, wrb);

    bfu* bufs[2] = {xA, xB};
    for (long s = 0; s < FINLEN; s += CH) {
        long CHc  = (FINLEN - s < CH) ? (FINLEN - s) : CH;   // multiple of 256
        int  len0 = (int)(CHc + RFIELD);

        int cur = 0;
        int L = len0;
        for (int i = 0; i < NLAYERS; ++i) {
            int d = 1 << (i & 7);
            int Lout = L - d;
            int tiles = (Lout + T_TILE - 1) / T_TILE;
            int NT    = (tiles + 63) / 64;                    // <=64 blocks/batch: 1 resident pass
            int bx    = (tiles + NT - 1) / NT;
            dim3 grid(bx, BATCH);
            const bfu* xi = bufs[cur];
            bfu*       xo = bufs[cur ^ 1];
            const bfu* wc  = wcat + (size_t)i * 128 * 128;
            const bfu* wr2 = wrb  + (size_t)i * 64 * 128;
            const float* bdl = bd + i * 128;
            const float* brl = br + i * 64;
            if (i == 0)
                layer_kernel<1><<<grid, 256, 0, stream>>>(xi, xo, wc, wr2, bdl, brl,
                    sig, W0, b0, Wf, partial, (int)s, d, L, Lout, (int)Rrows, NT, tiles);
            else if (i == NLAYERS - 1)
                layer_kernel<2><<<grid, 256, 0, stream>>>(xi, xo, wc, wr2, bdl, brl,
                    sig, W0, b0, Wf, partial, (int)s, d, L, Lout, (int)Rrows, NT, tiles);
            else
                layer_kernel<0><<<grid, 256, 0, stream>>>(xi, xo, wc, wr2, bdl, brl,
                    sig, W0, b0, Wf, partial, (int)s, d, L, Lout, (int)Rrows, NT, tiles);
            cur ^= 1;
            L = Lout;
        }
    }
    pool_reduce<<<(BATCH * 510 + 255) / 256, 256, 0, stream>>>(partial, bf, out);
}